// Round 9
// baseline (380.672 us; speedup 1.0000x reference)
//
#include <hip/hip_runtime.h>
#include <hip/hip_fp16.h>
#include <hip/hip_cooperative_groups.h>

namespace cg = cooperative_groups;

// Problem constants (from reference): N=50000, E=800000, dims 128->128->64->2.
#define IN_DIM 128
#define HID_DIM 128
#define OUT_DIM 64
#define BINW 128          // nodes per bin (dst >> 7)
#define BINSHIFT 7
#define MAXBIN 512        // LDS bound; nbin = ceil(N/128) = 391 for N=50000
#define HSTRIDE 400       // hist row stride (>= nbin)

// ---------------- fused CSR build (cooperative, grid = nbin blocks) ----------------
// P1 hist -> sync -> P2a per-bin scan -> sync -> P2b bin_base scan (blk0) + Wc (blk1)
// -> sync -> P3 scatter -> sync -> P4 per-bin fill (row_ptr, dinv, csr_src u16)
__global__ __launch_bounds__(256) void k_build(const int* __restrict__ src,
                                               const int* __restrict__ dst,
                                               int* __restrict__ hist,
                                               int* __restrict__ total,
                                               int* __restrict__ bin_base,
                                               unsigned int* __restrict__ ebin,
                                               int* __restrict__ row_ptr,
                                               unsigned short* __restrict__ csr_src,
                                               float* __restrict__ dinv,
                                               const float* __restrict__ W2,
                                               const float* __restrict__ Wfc,
                                               const float* __restrict__ b2,
                                               const float* __restrict__ bfc,
                                               float* __restrict__ Wc,
                                               float* __restrict__ bc,
                                               int E, int N, int nbin) {
    cg::grid_group grid = cg::this_grid();
    __shared__ int h[MAXBIN];      // P1 hist / P3 offsets
    __shared__ int part[256];      // scans
    __shared__ int cnt[BINW];      // P4
    __shared__ int excl[BINW];
    __shared__ int start[BINW];
    int t = threadIdx.x;
    int blk = blockIdx.x;
    int nblk = gridDim.x;          // == nbin
    int per = E / nblk;
    int ebeg = blk * per;
    int eend = (blk + 1 == nblk) ? E : ebeg + per;

    // ---- P1: per-block bin histogram ----
    for (int k = t; k < nbin; k += 256) h[k] = 0;
    __syncthreads();
    for (int i = ebeg + t; i < eend; i += 256)
        atomicAdd(&h[dst[i] >> BINSHIFT], 1);
    __syncthreads();
    for (int k = t; k < nbin; k += 256) hist[k * HSTRIDE + blk] = h[k];
    grid.sync();

    // ---- P2a: block k scans its bin's nblk per-block counts (exclusive) ----
    {
        int k = blk;
        int carry = 0;
        for (int base = 0; base < nblk; base += 256) {
            int i = base + t;
            int v = (i < nblk) ? hist[k * HSTRIDE + i] : 0;
            part[t] = v;
            __syncthreads();
            for (int off = 1; off < 256; off <<= 1) {
                int u = (t >= off) ? part[t - off] : 0;
                __syncthreads();
                part[t] += u;
                __syncthreads();
            }
            if (i < nblk) hist[k * HSTRIDE + i] = carry + part[t] - v;
            carry += part[255];
            __syncthreads();
        }
        if (t == 0) total[k] = carry;
    }
    grid.sync();

    // ---- P2b: block 0 scans bin totals; block 1 computes Wc = W2@Wfc, bc ----
    if (blk == 0) {
        int carry = 0;
        for (int base = 0; base < nbin; base += 256) {
            int i = base + t;
            int v = (i < nbin) ? total[i] : 0;
            part[t] = v;
            __syncthreads();
            for (int off = 1; off < 256; off <<= 1) {
                int u = (t >= off) ? part[t - off] : 0;
                __syncthreads();
                part[t] += u;
                __syncthreads();
            }
            if (i < nbin) bin_base[i] = carry + part[t] - v;
            carry += part[255];
            __syncthreads();
        }
        if (t == 0) bin_base[nbin] = carry;  // == E
    } else if (blk == 1) {
        int k = t >> 1, j = t & 1;
        float acc = 0.f;
#pragma unroll 8
        for (int m = 0; m < OUT_DIM; ++m) acc += W2[k * OUT_DIM + m] * Wfc[m * 2 + j];
        Wc[k * 2 + j] = acc;
        if (k == 0) {
            float b = 0.f;
#pragma unroll 8
            for (int m = 0; m < OUT_DIM; ++m) b += b2[m] * Wfc[m * 2 + j];
            bc[j] = b + bfc[j];
        }
    }
    grid.sync();

    // ---- P3: scatter packed edges into bin segments ----
    for (int k = t; k < nbin; k += 256)
        h[k] = bin_base[k] + hist[k * HSTRIDE + blk];
    __syncthreads();
    for (int i = ebeg + t; i < eend; i += 256) {
        unsigned int s = (unsigned int)src[i];
        unsigned int d = (unsigned int)dst[i];
        int pos = atomicAdd(&h[d >> BINSHIFT], 1);
        ebin[pos] = s | (d << 16);
    }
    grid.sync();

    // ---- P4: per-bin fine fill (block k owns bin k's segment) ----
    {
        int k = blk;
        int node0 = k * BINW;
        int nn = min(BINW, N - node0);
        if (t < BINW) cnt[t] = 0;
        __syncthreads();
        int eb = bin_base[k], ee = bin_base[k + 1];
        for (int i = eb + t; i < ee; i += 256)
            atomicAdd(&cnt[(ebin[i] >> 16) - node0], 1);
        __syncthreads();
        if (t < BINW) excl[t] = (t < nn) ? cnt[t] : 0;
        __syncthreads();
        for (int off = 1; off < BINW; off <<= 1) {
            int u = 0;
            if (t < BINW && t >= off) u = excl[t - off];
            __syncthreads();
            if (t < BINW) excl[t] += u;   // inclusive scan
            __syncthreads();
        }
        if (t < nn) {
            int deg = cnt[t];
            int e0 = eb + excl[t] - deg;  // exclusive
            start[t] = e0;
            row_ptr[node0 + t] = e0;
            dinv[node0 + t] = rsqrtf((float)deg + 1.0f);
            cnt[t] = 0;                   // reuse as fill counter
        }
        if (k == nbin - 1 && t == 0) row_ptr[N] = ee;
        __syncthreads();
        for (int i = eb + t; i < ee; i += 256) {
            unsigned int e = ebin[i];
            int dl = (int)(e >> 16) - node0;
            int slot = start[dl] + atomicAdd(&cnt[dl], 1);
            csr_src[slot] = (unsigned short)(e & 0xffffu);
        }
    }
}

// ---------------- GEMM1: xw1h = fp16(dinv[row] * (x @ W1)) ----------------
// Block tile 128x128, 256 threads, 8 rows x 8 cols per thread. A from global
// (16-lane broadcast). LDS = W only (64 KB) -> 2 blocks/CU.
__global__ __launch_bounds__(256) void k_gemm1(const float* __restrict__ x,
                                               const float* __restrict__ W,
                                               const float* __restrict__ dinv,
                                               __half* __restrict__ xwh, int N) {
    __shared__ float Ws[128][128];   // [k][col]
    int tid = threadIdx.x;
    const float4* W4 = (const float4*)W;
    float4* Ws4 = (float4*)&Ws[0][0];
#pragma unroll
    for (int i = 0; i < 16; ++i) Ws4[tid + 256 * i] = W4[tid + 256 * i];
    __syncthreads();
    int tx = tid & 15, ty = tid >> 4;
    int row0 = blockIdx.x * 128;
    int rows[8];
    const float* xr[8];
#pragma unroll
    for (int j = 0; j < 8; ++j) {
        int row = row0 + ty + 16 * j;
        rows[j] = row;
        if (row > N - 1) row = N - 1;
        xr[j] = x + (size_t)row * IN_DIM;
    }
    float4 aclo[8], achi[8];
#pragma unroll
    for (int j = 0; j < 8; ++j) {
        aclo[j] = make_float4(0.f, 0.f, 0.f, 0.f);
        achi[j] = make_float4(0.f, 0.f, 0.f, 0.f);
    }
#pragma unroll 2
    for (int k4 = 0; k4 < 32; ++k4) {
        float4 av[8];
#pragma unroll
        for (int j = 0; j < 8; ++j) av[j] = *(const float4*)(xr[j] + k4 * 4);
#pragma unroll
        for (int kk = 0; kk < 4; ++kk) {
            float4 blo = *(const float4*)&Ws[k4 * 4 + kk][4 * tx];
            float4 bhi = *(const float4*)&Ws[k4 * 4 + kk][64 + 4 * tx];
#pragma unroll
            for (int j = 0; j < 8; ++j) {
                float a = (kk == 0) ? av[j].x : (kk == 1) ? av[j].y : (kk == 2) ? av[j].z : av[j].w;
                aclo[j].x += a * blo.x; aclo[j].y += a * blo.y;
                aclo[j].z += a * blo.z; aclo[j].w += a * blo.w;
                achi[j].x += a * bhi.x; achi[j].y += a * bhi.y;
                achi[j].z += a * bhi.z; achi[j].w += a * bhi.w;
            }
        }
    }
#pragma unroll
    for (int j = 0; j < 8; ++j) {
        if (rows[j] < N) {
            float dd = dinv[rows[j]];
            union { __half2 h[2]; uint2 u; } lo, hi;
            lo.h[0] = __floats2half2_rn(aclo[j].x * dd, aclo[j].y * dd);
            lo.h[1] = __floats2half2_rn(aclo[j].z * dd, aclo[j].w * dd);
            hi.h[0] = __floats2half2_rn(achi[j].x * dd, achi[j].y * dd);
            hi.h[1] = __floats2half2_rn(achi[j].z * dd, achi[j].w * dd);
            uint2* p = (uint2*)(xwh + (size_t)rows[j] * HID_DIM);
            p[tx] = lo.u;
            p[16 + tx] = hi.u;
        }
    }
}

// ---------------- Layer-1 aggregation + bias + ReLU + (h1 @ Wc) epilogue ----------------
// h1 = relu(dinv[d]*(sum_s xwh[s] + xwh[d]) + b1)   (xwh pre-scaled by dinv)
// z[d] = dinv[d] * (h1 @ Wc)    -- only 2 floats written per node
__global__ __launch_bounds__(256) void k_agg1z(const int* __restrict__ row_ptr,
                                               const unsigned short* __restrict__ csr_src,
                                               const float* __restrict__ dinv,
                                               const __half* __restrict__ xwh,
                                               const float* __restrict__ b1,
                                               const float* __restrict__ Wc,
                                               float* __restrict__ z, int N) {
    constexpr int F = HID_DIM;
    constexpr int L = F / 8;       // 16 lanes per row, 16B/lane
    constexpr int EPW = 64 / L;    // 4 edge slots per wave
    __shared__ float Wcs[HID_DIM * 2];
    int tid = threadIdx.x;
    if (tid < 64) ((float4*)Wcs)[tid] = ((const float4*)Wc)[tid];
    __syncthreads();
    int node = (blockIdx.x * 256 + tid) >> 6;
    if (node >= N) return;
    int lane = tid & 63;
    int sub = lane / L;
    int c   = lane % L;
    int beg = row_ptr[node], end = row_ptr[node + 1];
    // hoisted loads (overlap with gather)
    float dd = dinv[node];
    uint4 us = *(const uint4*)(xwh + (size_t)node * F + c * 8);
    float4 b1a = *(const float4*)(b1 + c * 8);
    float4 b1b = *(const float4*)(b1 + c * 8 + 4);
    float a0 = 0.f, a1 = 0.f, a2 = 0.f, a3 = 0.f;
    float a4 = 0.f, a5 = 0.f, a6 = 0.f, a7 = 0.f;
    int j = beg + sub;
    for (; j + EPW < end; j += 2 * EPW) {
        int s0 = csr_src[j];
        int s1 = csr_src[j + EPW];
        uint4 u0 = *(const uint4*)(xwh + (size_t)s0 * F + c * 8);
        uint4 u1 = *(const uint4*)(xwh + (size_t)s1 * F + c * 8);
        float2 v0 = __half22float2(*(__half2*)&u0.x);
        float2 v1 = __half22float2(*(__half2*)&u0.y);
        float2 v2 = __half22float2(*(__half2*)&u0.z);
        float2 v3 = __half22float2(*(__half2*)&u0.w);
        a0 += v0.x; a1 += v0.y; a2 += v1.x; a3 += v1.y;
        a4 += v2.x; a5 += v2.y; a6 += v3.x; a7 += v3.y;
        v0 = __half22float2(*(__half2*)&u1.x);
        v1 = __half22float2(*(__half2*)&u1.y);
        v2 = __half22float2(*(__half2*)&u1.z);
        v3 = __half22float2(*(__half2*)&u1.w);
        a0 += v0.x; a1 += v0.y; a2 += v1.x; a3 += v1.y;
        a4 += v2.x; a5 += v2.y; a6 += v3.x; a7 += v3.y;
    }
    if (j < end) {
        int s = csr_src[j];
        uint4 u = *(const uint4*)(xwh + (size_t)s * F + c * 8);
        float2 v0 = __half22float2(*(__half2*)&u.x);
        float2 v1 = __half22float2(*(__half2*)&u.y);
        float2 v2 = __half22float2(*(__half2*)&u.z);
        float2 v3 = __half22float2(*(__half2*)&u.w);
        a0 += v0.x; a1 += v0.y; a2 += v1.x; a3 += v1.y;
        a4 += v2.x; a5 += v2.y; a6 += v3.x; a7 += v3.y;
    }
#pragma unroll
    for (int off = L; off < 64; off <<= 1) {
        a0 += __shfl_xor(a0, off); a1 += __shfl_xor(a1, off);
        a2 += __shfl_xor(a2, off); a3 += __shfl_xor(a3, off);
        a4 += __shfl_xor(a4, off); a5 += __shfl_xor(a5, off);
        a6 += __shfl_xor(a6, off); a7 += __shfl_xor(a7, off);
    }
    // all lanes now hold the full column sums for their c
    float2 v0 = __half22float2(*(__half2*)&us.x);
    float2 v1 = __half22float2(*(__half2*)&us.y);
    float2 v2 = __half22float2(*(__half2*)&us.z);
    float2 v3 = __half22float2(*(__half2*)&us.w);
    float h[8];
    h[0] = fmaxf((a0 + v0.x) * dd + b1a.x, 0.f);
    h[1] = fmaxf((a1 + v0.y) * dd + b1a.y, 0.f);
    h[2] = fmaxf((a2 + v1.x) * dd + b1a.z, 0.f);
    h[3] = fmaxf((a3 + v1.y) * dd + b1a.w, 0.f);
    h[4] = fmaxf((a4 + v2.x) * dd + b1b.x, 0.f);
    h[5] = fmaxf((a5 + v2.y) * dd + b1b.y, 0.f);
    h[6] = fmaxf((a6 + v3.x) * dd + b1b.z, 0.f);
    h[7] = fmaxf((a7 + v3.y) * dd + b1b.w, 0.f);
    float o0 = 0.f, o1 = 0.f;
#pragma unroll
    for (int k = 0; k < 8; ++k) {
        o0 += h[k] * Wcs[(c * 8 + k) * 2 + 0];
        o1 += h[k] * Wcs[(c * 8 + k) * 2 + 1];
    }
    // reduce the 16 c-lanes (xor<16 stays within each 16-lane group)
#pragma unroll
    for (int off = 1; off < L; off <<= 1) {
        o0 += __shfl_xor(o0, off);
        o1 += __shfl_xor(o1, off);
    }
    if (lane == 0) {
        float2 r; r.x = o0 * dd; r.y = o1 * dd;
        *(float2*)(z + (size_t)node * 2) = r;
    }
}

// ---------------- Layer-2 aggregation on z (2 floats/node) + bias + leaky ----------------
__global__ __launch_bounds__(256) void k_agg2(const int* __restrict__ row_ptr,
                                              const unsigned short* __restrict__ csr_src,
                                              const float* __restrict__ dinv,
                                              const float* __restrict__ z,
                                              const float* __restrict__ bc,
                                              float* __restrict__ out, int N) {
    int tid = threadIdx.x;
    int gwave = (blockIdx.x * 256 + tid) >> 6;
    int lane = tid & 63;
    int grp = lane >> 3, li = lane & 7;
    int node = gwave * 8 + grp;
    if (node >= N) return;
    int beg = row_ptr[node], end = row_ptr[node + 1];
    float s0 = 0.f, s1 = 0.f;
    int j = beg + li;
    for (; j + 8 < end; j += 16) {
        int sa = csr_src[j];
        int sb = csr_src[j + 8];
        float2 za = *(const float2*)(z + (size_t)sa * 2);
        float2 zb = *(const float2*)(z + (size_t)sb * 2);
        s0 += za.x + zb.x; s1 += za.y + zb.y;
    }
    if (j < end) {
        int s = csr_src[j];
        float2 zv = *(const float2*)(z + (size_t)s * 2);
        s0 += zv.x; s1 += zv.y;
    }
#pragma unroll
    for (int off = 1; off < 8; off <<= 1) {
        s0 += __shfl_xor(s0, off);
        s1 += __shfl_xor(s1, off);
    }
    if (li == 0) {
        float2 zs = *(const float2*)(z + (size_t)node * 2);
        float dd = dinv[node];
        float o0 = (s0 + zs.x) * dd + bc[0];
        float o1 = (s1 + zs.y) * dd + bc[1];
        float2 r;
        r.x = o0 > 0.f ? o0 : 0.01f * o0;
        r.y = o1 > 0.f ? o1 : 0.01f * o1;
        *(float2*)(out + (size_t)node * 2) = r;
    }
}

extern "C" void kernel_launch(void* const* d_in, const int* in_sizes, int n_in,
                              void* d_out, int out_size, void* d_ws, size_t ws_size,
                              hipStream_t stream) {
    const float* x   = (const float*)d_in[0];
    const int*   ei  = (const int*)d_in[1];
    const float* W1  = (const float*)d_in[2];
    const float* b1  = (const float*)d_in[3];
    const float* W2  = (const float*)d_in[4];
    const float* b2  = (const float*)d_in[5];
    const float* Wfc = (const float*)d_in[6];
    const float* bfc = (const float*)d_in[7];

    const int N = in_sizes[0] / IN_DIM;   // 50000
    const int E = in_sizes[1] / 2;        // 800000
    const int* src = ei;
    const int* dst = ei + E;
    const int nbin = (N + BINW - 1) / BINW;  // 391

    // Workspace layout (256B-aligned regions):
    char* base = (char*)d_ws;
    size_t off = 0;
    auto take = [&](size_t bytes) { size_t o = off; off = (off + bytes + 255) & ~(size_t)255; return (void*)(base + o); };
    int*    row_ptr  = (int*)take((size_t)(N + 1) * 4);
    unsigned short* csr_src = (unsigned short*)take((size_t)E * 2);
    int*    hist     = (int*)take((size_t)nbin * HSTRIDE * 4);
    int*    total    = (int*)take((size_t)nbin * 4);
    int*    bin_base = (int*)take((size_t)(nbin + 1) * 4);
    unsigned int* ebin = (unsigned int*)take((size_t)E * 4);
    float*  dinv     = (float*)take((size_t)N * 4);
    __half* xw1h     = (__half*)take((size_t)N * HID_DIM * 2);   // layer-1 messages
    float*  zbuf     = (float*)take((size_t)N * 2 * 4);          // z = dinv*(h1@Wc)
    float*  Wc       = (float*)take((size_t)HID_DIM * 2 * 4);
    float*  bc       = (float*)take(2 * 4);

    // Fused CSR build + Wc fold (one cooperative launch; 391 blocks, tiny LDS
    // and VGPR so co-residency on 256 CUs is guaranteed)
    {
        int E_ = E, N_ = N, nbin_ = nbin;
        void* args[] = {(void*)&src, (void*)&dst, (void*)&hist, (void*)&total,
                        (void*)&bin_base, (void*)&ebin, (void*)&row_ptr,
                        (void*)&csr_src, (void*)&dinv,
                        (void*)&W2, (void*)&Wfc, (void*)&b2, (void*)&bfc,
                        (void*)&Wc, (void*)&bc,
                        (void*)&E_, (void*)&N_, (void*)&nbin_};
        hipLaunchCooperativeKernel((void*)k_build, dim3(nbin), dim3(256),
                                   args, 0, stream);
    }

    const int nTile = (N + 127) / 128;

    // Layer 1 GEMM
    k_gemm1<<<nTile, 256, 0, stream>>>(x, W1, dinv, xw1h, N);
    // Layer-1 aggregation + relu + folded 128x2 GEMV -> z
    k_agg1z<<<(N + 3) / 4, 256, 0, stream>>>(row_ptr, csr_src, dinv, xw1h, b1, Wc, zbuf, N);
    // Layer-2 aggregation on z + bias + leaky -> out
    const int nAgg2 = ((N + 7) / 8 * 64 + 255) / 256;
    k_agg2<<<nAgg2, 256, 0, stream>>>(row_ptr, csr_src, dinv, zbuf, bc, (float*)d_out, N);
}

// Round 10
// 178.948 us; speedup vs baseline: 2.1273x; 2.1273x over previous
//
#include <hip/hip_runtime.h>
#include <hip/hip_fp16.h>

// Problem constants (from reference): N=50000, E=800000, dims 128->128->64->2.
#define IN_DIM 128
#define HID_DIM 128
#define OUT_DIM 64
#define BINW 128          // nodes per bin (dst >> 7)
#define BINSHIFT 7
#define MAXBIN 512        // LDS capacity bound; nbin = ceil(N/128) = 391 for N=50000
#define EBLK 256          // blocks in edge passes

// ---------------- P1: per-block bin histogram ----------------
__global__ __launch_bounds__(256) void k_bin_hist(const int* __restrict__ dst,
                                                  int* __restrict__ hist, int E, int nbin) {
    __shared__ int h[MAXBIN];
    int tid = threadIdx.x;
    for (int k = tid; k < nbin; k += 256) h[k] = 0;
    __syncthreads();
    int per = E / gridDim.x;
    int base = blockIdx.x * per;
    int end = (blockIdx.x + 1 == gridDim.x) ? E : base + per;
    for (int i = base + tid; i < end; i += 256)
        atomicAdd(&h[dst[i] >> BINSHIFT], 1);
    __syncthreads();
    for (int k = tid; k < nbin; k += 256) hist[k * EBLK + blockIdx.x] = h[k];
}

// ---------------- P2a: scan each bin's 256 per-block counts ----------------
__global__ __launch_bounds__(256) void k_bin_scan(int* __restrict__ hist,
                                                  int* __restrict__ total) {
    __shared__ int part[256];
    int k = blockIdx.x;
    int t = threadIdx.x;
    int v = hist[k * EBLK + t];
    part[t] = v;
    __syncthreads();
    for (int off = 1; off < 256; off <<= 1) {
        int u = (t >= off) ? part[t - off] : 0;
        __syncthreads();
        part[t] += u;
        __syncthreads();
    }
    hist[k * EBLK + t] = part[t] - v;  // exclusive within bin
    if (t == 255) total[k] = part[255];
}

// ---------------- P2b: exclusive scan of bin totals ----------------
__global__ __launch_bounds__(256) void k_bin_base(const int* __restrict__ total,
                                                  int* __restrict__ bin_base, int nbin) {
    __shared__ int part[256];
    int t = threadIdx.x;
    int carry = 0;
    for (int base = 0; base < nbin; base += 256) {
        int i = base + t;
        int v = (i < nbin) ? total[i] : 0;
        part[t] = v;
        __syncthreads();
        for (int off = 1; off < 256; off <<= 1) {
            int u = (t >= off) ? part[t - off] : 0;
            __syncthreads();
            part[t] += u;
            __syncthreads();
        }
        if (i < nbin) bin_base[i] = carry + part[t] - v;
        carry += part[255];
        __syncthreads();
    }
    if (t == 0) bin_base[nbin] = carry;  // == E
}

// ---------------- P3: scatter packed edges into bin segments ----------------
__global__ __launch_bounds__(256) void k_bin_scatter(const int* __restrict__ src,
                                                     const int* __restrict__ dst,
                                                     const int* __restrict__ hist,
                                                     const int* __restrict__ bin_base,
                                                     unsigned int* __restrict__ ebin,
                                                     int E, int nbin) {
    __shared__ int off[MAXBIN];
    int tid = threadIdx.x;
    for (int k = tid; k < nbin; k += 256)
        off[k] = bin_base[k] + hist[k * EBLK + blockIdx.x];
    __syncthreads();
    int per = E / gridDim.x;
    int base = blockIdx.x * per;
    int end = (blockIdx.x + 1 == gridDim.x) ? E : base + per;
    for (int i = base + tid; i < end; i += 256) {
        unsigned int s = (unsigned int)src[i];
        unsigned int d = (unsigned int)dst[i];
        int pos = atomicAdd(&off[d >> BINSHIFT], 1);
        ebin[pos] = s | (d << 16);
    }
}

// ---------------- P4: per-bin fine fill — row_ptr, dinv, csr_src (u16) ----------------
__global__ __launch_bounds__(256) void k_bin_fill(const unsigned int* __restrict__ ebin,
                                                  const int* __restrict__ bin_base,
                                                  int* __restrict__ row_ptr,
                                                  unsigned short* __restrict__ csr_src,
                                                  float* __restrict__ dinv, int N, int nbin) {
    __shared__ int cnt[BINW];
    __shared__ int excl[BINW];
    __shared__ int start[BINW];
    int k = blockIdx.x;
    int node0 = k * BINW;
    int nn = min(BINW, N - node0);
    int t = threadIdx.x;
    if (t < BINW) cnt[t] = 0;
    __syncthreads();
    int eb = bin_base[k], ee = bin_base[k + 1];
    for (int i = eb + t; i < ee; i += 256)
        atomicAdd(&cnt[(ebin[i] >> 16) - node0], 1);
    __syncthreads();
    if (t < BINW) excl[t] = (t < nn) ? cnt[t] : 0;
    __syncthreads();
    for (int off = 1; off < BINW; off <<= 1) {
        int u = 0;
        if (t < BINW && t >= off) u = excl[t - off];
        __syncthreads();
        if (t < BINW) excl[t] += u;   // inclusive scan
        __syncthreads();
    }
    if (t < nn) {
        int deg = cnt[t];
        int e0 = eb + excl[t] - deg;  // exclusive
        start[t] = e0;
        row_ptr[node0 + t] = e0;
        dinv[node0 + t] = rsqrtf((float)deg + 1.0f);
        cnt[t] = 0;                   // reuse as fill counter
    }
    if (k == nbin - 1 && t == 0) row_ptr[N] = ee;
    __syncthreads();
    for (int i = eb + t; i < ee; i += 256) {
        unsigned int e = ebin[i];
        int dl = (int)(e >> 16) - node0;
        int slot = start[dl] + atomicAdd(&cnt[dl], 1);
        csr_src[slot] = (unsigned short)(e & 0xffffu);
    }
}

// ---------------- Wc = W2 @ Wfc (128x2), bc = b2 @ Wfc + bfc ----------------
__global__ __launch_bounds__(256) void k_wc(const float* __restrict__ W2,
                                            const float* __restrict__ Wfc,
                                            const float* __restrict__ b2,
                                            const float* __restrict__ bfc,
                                            float* __restrict__ Wc,
                                            float* __restrict__ bc) {
    int t = threadIdx.x;
    int k = t >> 1, j = t & 1;
    float acc = 0.f;
#pragma unroll 8
    for (int m = 0; m < OUT_DIM; ++m) acc += W2[k * OUT_DIM + m] * Wfc[m * 2 + j];
    Wc[k * 2 + j] = acc;
    if (k == 0) {
        float b = 0.f;
#pragma unroll 8
        for (int m = 0; m < OUT_DIM; ++m) b += b2[m] * Wfc[m * 2 + j];
        bc[j] = b + bfc[j];
    }
}

// ---------------- GEMM1: xw1h = fp16(dinv[row] * (x @ W1)) ----------------
// Block tile 128x128, 256 threads, 8 rows x 8 cols per thread. A from global
// (16-lane broadcast). LDS = W only (64 KB) -> 2 blocks/CU.
__global__ __launch_bounds__(256) void k_gemm1(const float* __restrict__ x,
                                               const float* __restrict__ W,
                                               const float* __restrict__ dinv,
                                               __half* __restrict__ xwh, int N) {
    __shared__ float Ws[128][128];   // [k][col]
    int tid = threadIdx.x;
    const float4* W4 = (const float4*)W;
    float4* Ws4 = (float4*)&Ws[0][0];
#pragma unroll
    for (int i = 0; i < 16; ++i) Ws4[tid + 256 * i] = W4[tid + 256 * i];
    __syncthreads();
    int tx = tid & 15, ty = tid >> 4;
    int row0 = blockIdx.x * 128;
    int rows[8];
    const float* xr[8];
#pragma unroll
    for (int j = 0; j < 8; ++j) {
        int row = row0 + ty + 16 * j;
        rows[j] = row;
        if (row > N - 1) row = N - 1;
        xr[j] = x + (size_t)row * IN_DIM;
    }
    float4 aclo[8], achi[8];
#pragma unroll
    for (int j = 0; j < 8; ++j) {
        aclo[j] = make_float4(0.f, 0.f, 0.f, 0.f);
        achi[j] = make_float4(0.f, 0.f, 0.f, 0.f);
    }
#pragma unroll 2
    for (int k4 = 0; k4 < 32; ++k4) {
        float4 av[8];
#pragma unroll
        for (int j = 0; j < 8; ++j) av[j] = *(const float4*)(xr[j] + k4 * 4);
#pragma unroll
        for (int kk = 0; kk < 4; ++kk) {
            float4 blo = *(const float4*)&Ws[k4 * 4 + kk][4 * tx];
            float4 bhi = *(const float4*)&Ws[k4 * 4 + kk][64 + 4 * tx];
#pragma unroll
            for (int j = 0; j < 8; ++j) {
                float a = (kk == 0) ? av[j].x : (kk == 1) ? av[j].y : (kk == 2) ? av[j].z : av[j].w;
                aclo[j].x += a * blo.x; aclo[j].y += a * blo.y;
                aclo[j].z += a * blo.z; aclo[j].w += a * blo.w;
                achi[j].x += a * bhi.x; achi[j].y += a * bhi.y;
                achi[j].z += a * bhi.z; achi[j].w += a * bhi.w;
            }
        }
    }
#pragma unroll
    for (int j = 0; j < 8; ++j) {
        if (rows[j] < N) {
            float dd = dinv[rows[j]];
            union { __half2 h[2]; uint2 u; } lo, hi;
            lo.h[0] = __floats2half2_rn(aclo[j].x * dd, aclo[j].y * dd);
            lo.h[1] = __floats2half2_rn(aclo[j].z * dd, aclo[j].w * dd);
            hi.h[0] = __floats2half2_rn(achi[j].x * dd, achi[j].y * dd);
            hi.h[1] = __floats2half2_rn(achi[j].z * dd, achi[j].w * dd);
            uint2* p = (uint2*)(xwh + (size_t)rows[j] * HID_DIM);
            p[tx] = lo.u;
            p[16 + tx] = hi.u;
        }
    }
}

// ---------------- Layer-1 aggregation + bias + ReLU + (h1 @ Wc) epilogue ----------------
// h1 = relu(dinv[d]*(sum_s xwh[s] + xwh[d]) + b1)   (xwh pre-scaled by dinv)
// z[d] = dinv[d] * (h1 @ Wc)    -- only 2 floats written per node
__global__ __launch_bounds__(256) void k_agg1z(const int* __restrict__ row_ptr,
                                               const unsigned short* __restrict__ csr_src,
                                               const float* __restrict__ dinv,
                                               const __half* __restrict__ xwh,
                                               const float* __restrict__ b1,
                                               const float* __restrict__ Wc,
                                               float* __restrict__ z, int N) {
    constexpr int F = HID_DIM;
    constexpr int L = F / 8;       // 16 lanes per row, 16B/lane
    constexpr int EPW = 64 / L;    // 4 edge slots per wave
    __shared__ float Wcs[HID_DIM * 2];
    int tid = threadIdx.x;
    if (tid < 64) ((float4*)Wcs)[tid] = ((const float4*)Wc)[tid];
    __syncthreads();
    int node = (blockIdx.x * 256 + tid) >> 6;
    if (node >= N) return;
    int lane = tid & 63;
    int sub = lane / L;
    int c   = lane % L;
    int beg = row_ptr[node], end = row_ptr[node + 1];
    // hoisted loads (overlap with gather)
    float dd = dinv[node];
    uint4 us = *(const uint4*)(xwh + (size_t)node * F + c * 8);
    float4 b1a = *(const float4*)(b1 + c * 8);
    float4 b1b = *(const float4*)(b1 + c * 8 + 4);
    float a0 = 0.f, a1 = 0.f, a2 = 0.f, a3 = 0.f;
    float a4 = 0.f, a5 = 0.f, a6 = 0.f, a7 = 0.f;
    int j = beg + sub;
    for (; j + EPW < end; j += 2 * EPW) {
        int s0 = csr_src[j];
        int s1 = csr_src[j + EPW];
        uint4 u0 = *(const uint4*)(xwh + (size_t)s0 * F + c * 8);
        uint4 u1 = *(const uint4*)(xwh + (size_t)s1 * F + c * 8);
        float2 v0 = __half22float2(*(__half2*)&u0.x);
        float2 v1 = __half22float2(*(__half2*)&u0.y);
        float2 v2 = __half22float2(*(__half2*)&u0.z);
        float2 v3 = __half22float2(*(__half2*)&u0.w);
        a0 += v0.x; a1 += v0.y; a2 += v1.x; a3 += v1.y;
        a4 += v2.x; a5 += v2.y; a6 += v3.x; a7 += v3.y;
        v0 = __half22float2(*(__half2*)&u1.x);
        v1 = __half22float2(*(__half2*)&u1.y);
        v2 = __half22float2(*(__half2*)&u1.z);
        v3 = __half22float2(*(__half2*)&u1.w);
        a0 += v0.x; a1 += v0.y; a2 += v1.x; a3 += v1.y;
        a4 += v2.x; a5 += v2.y; a6 += v3.x; a7 += v3.y;
    }
    if (j < end) {
        int s = csr_src[j];
        uint4 u = *(const uint4*)(xwh + (size_t)s * F + c * 8);
        float2 v0 = __half22float2(*(__half2*)&u.x);
        float2 v1 = __half22float2(*(__half2*)&u.y);
        float2 v2 = __half22float2(*(__half2*)&u.z);
        float2 v3 = __half22float2(*(__half2*)&u.w);
        a0 += v0.x; a1 += v0.y; a2 += v1.x; a3 += v1.y;
        a4 += v2.x; a5 += v2.y; a6 += v3.x; a7 += v3.y;
    }
#pragma unroll
    for (int off = L; off < 64; off <<= 1) {
        a0 += __shfl_xor(a0, off); a1 += __shfl_xor(a1, off);
        a2 += __shfl_xor(a2, off); a3 += __shfl_xor(a3, off);
        a4 += __shfl_xor(a4, off); a5 += __shfl_xor(a5, off);
        a6 += __shfl_xor(a6, off); a7 += __shfl_xor(a7, off);
    }
    // all lanes now hold the full column sums for their c
    float2 v0 = __half22float2(*(__half2*)&us.x);
    float2 v1 = __half22float2(*(__half2*)&us.y);
    float2 v2 = __half22float2(*(__half2*)&us.z);
    float2 v3 = __half22float2(*(__half2*)&us.w);
    float h[8];
    h[0] = fmaxf((a0 + v0.x) * dd + b1a.x, 0.f);
    h[1] = fmaxf((a1 + v0.y) * dd + b1a.y, 0.f);
    h[2] = fmaxf((a2 + v1.x) * dd + b1a.z, 0.f);
    h[3] = fmaxf((a3 + v1.y) * dd + b1a.w, 0.f);
    h[4] = fmaxf((a4 + v2.x) * dd + b1b.x, 0.f);
    h[5] = fmaxf((a5 + v2.y) * dd + b1b.y, 0.f);
    h[6] = fmaxf((a6 + v3.x) * dd + b1b.z, 0.f);
    h[7] = fmaxf((a7 + v3.y) * dd + b1b.w, 0.f);
    float o0 = 0.f, o1 = 0.f;
#pragma unroll
    for (int k = 0; k < 8; ++k) {
        o0 += h[k] * Wcs[(c * 8 + k) * 2 + 0];
        o1 += h[k] * Wcs[(c * 8 + k) * 2 + 1];
    }
    // reduce the 16 c-lanes (xor<16 stays within each 16-lane group)
#pragma unroll
    for (int off = 1; off < L; off <<= 1) {
        o0 += __shfl_xor(o0, off);
        o1 += __shfl_xor(o1, off);
    }
    if (lane == 0) {
        float2 r; r.x = o0 * dd; r.y = o1 * dd;
        *(float2*)(z + (size_t)node * 2) = r;
    }
}

// ---------------- Layer-2 aggregation on z (2 floats/node) + bias + leaky ----------------
__global__ __launch_bounds__(256) void k_agg2(const int* __restrict__ row_ptr,
                                              const unsigned short* __restrict__ csr_src,
                                              const float* __restrict__ dinv,
                                              const float* __restrict__ z,
                                              const float* __restrict__ bc,
                                              float* __restrict__ out, int N) {
    int tid = threadIdx.x;
    int gwave = (blockIdx.x * 256 + tid) >> 6;
    int lane = tid & 63;
    int grp = lane >> 3, li = lane & 7;
    int node = gwave * 8 + grp;
    if (node >= N) return;
    int beg = row_ptr[node], end = row_ptr[node + 1];
    float s0 = 0.f, s1 = 0.f;
    int j = beg + li;
    for (; j + 8 < end; j += 16) {
        int sa = csr_src[j];
        int sb = csr_src[j + 8];
        float2 za = *(const float2*)(z + (size_t)sa * 2);
        float2 zb = *(const float2*)(z + (size_t)sb * 2);
        s0 += za.x + zb.x; s1 += za.y + zb.y;
    }
    if (j < end) {
        int s = csr_src[j];
        float2 zv = *(const float2*)(z + (size_t)s * 2);
        s0 += zv.x; s1 += zv.y;
    }
#pragma unroll
    for (int off = 1; off < 8; off <<= 1) {
        s0 += __shfl_xor(s0, off);
        s1 += __shfl_xor(s1, off);
    }
    if (li == 0) {
        float2 zs = *(const float2*)(z + (size_t)node * 2);
        float dd = dinv[node];
        float o0 = (s0 + zs.x) * dd + bc[0];
        float o1 = (s1 + zs.y) * dd + bc[1];
        float2 r;
        r.x = o0 > 0.f ? o0 : 0.01f * o0;
        r.y = o1 > 0.f ? o1 : 0.01f * o1;
        *(float2*)(out + (size_t)node * 2) = r;
    }
}

extern "C" void kernel_launch(void* const* d_in, const int* in_sizes, int n_in,
                              void* d_out, int out_size, void* d_ws, size_t ws_size,
                              hipStream_t stream) {
    const float* x   = (const float*)d_in[0];
    const int*   ei  = (const int*)d_in[1];
    const float* W1  = (const float*)d_in[2];
    const float* b1  = (const float*)d_in[3];
    const float* W2  = (const float*)d_in[4];
    const float* b2  = (const float*)d_in[5];
    const float* Wfc = (const float*)d_in[6];
    const float* bfc = (const float*)d_in[7];

    const int N = in_sizes[0] / IN_DIM;   // 50000
    const int E = in_sizes[1] / 2;        // 800000
    const int* src = ei;
    const int* dst = ei + E;
    const int nbin = (N + BINW - 1) / BINW;  // 391

    // Workspace layout (256B-aligned regions):
    char* base = (char*)d_ws;
    size_t off = 0;
    auto take = [&](size_t bytes) { size_t o = off; off = (off + bytes + 255) & ~(size_t)255; return (void*)(base + o); };
    int*    row_ptr  = (int*)take((size_t)(N + 1) * 4);
    unsigned short* csr_src = (unsigned short*)take((size_t)E * 2);
    int*    hist     = (int*)take((size_t)nbin * EBLK * 4);
    int*    total    = (int*)take((size_t)nbin * 4);
    int*    bin_base = (int*)take((size_t)(nbin + 1) * 4);
    unsigned int* ebin = (unsigned int*)take((size_t)E * 4);
    float*  dinv     = (float*)take((size_t)N * 4);
    __half* xw1h     = (__half*)take((size_t)N * HID_DIM * 2);   // layer-1 messages
    float*  zbuf     = (float*)take((size_t)N * 2 * 4);          // z = dinv*(h1@Wc)
    float*  Wc       = (float*)take((size_t)HID_DIM * 2 * 4);
    float*  bc       = (float*)take(2 * 4);

    // CSR build (split kernels — cooperative grid.sync costs ~50us/sync on
    // MI355X (R9 post-mortem), far more than the launch gaps it saves)
    k_bin_hist<<<EBLK, 256, 0, stream>>>(dst, hist, E, nbin);
    k_bin_scan<<<nbin, 256, 0, stream>>>(hist, total);
    k_bin_base<<<1, 256, 0, stream>>>(total, bin_base, nbin);
    k_bin_scatter<<<EBLK, 256, 0, stream>>>(src, dst, hist, bin_base, ebin, E, nbin);
    k_bin_fill<<<nbin, 256, 0, stream>>>(ebin, bin_base, row_ptr, csr_src, dinv, N, nbin);

    // Fold W2@Wfc (128x2) + bias constant
    k_wc<<<1, 256, 0, stream>>>(W2, Wfc, b2, bfc, Wc, bc);

    const int nTile = (N + 127) / 128;

    // Layer 1 GEMM
    k_gemm1<<<nTile, 256, 0, stream>>>(x, W1, dinv, xw1h, N);
    // Layer-1 aggregation + relu + folded 128x2 GEMV -> z
    k_agg1z<<<(N + 3) / 4, 256, 0, stream>>>(row_ptr, csr_src, dinv, xw1h, b1, Wc, zbuf, N);
    // Layer-2 aggregation on z + bias + leaky -> out
    const int nAgg2 = ((N + 7) / 8 * 64 + 255) / 256;
    k_agg2<<<nAgg2, 256, 0, stream>>>(row_ptr, csr_src, dinv, zbuf, bc, (float*)d_out, N);
}

// Round 11
// 177.678 us; speedup vs baseline: 2.1425x; 1.0071x over previous
//
#include <hip/hip_runtime.h>
#include <hip/hip_fp16.h>

// Problem constants (from reference): N=50000, E=800000, dims 128->128->64->2.
#define IN_DIM 128
#define HID_DIM 128
#define OUT_DIM 64
#define BINW 128          // nodes per bin (dst >> 7)
#define BINSHIFT 7
#define MAXBIN 512        // LDS bound; nbin = ceil(N/128) = 391 for N=50000
#define CAP 4096          // fixed bin capacity (mean 2046; overflow handled correctly)
#define CNTSTRIDE 16      // bin_cnt stride in ints (one 64B line per counter)

// ---------------- build pass 1: hist + atomic reserve + scatter into bins ----------------
__global__ __launch_bounds__(256) void k_scatter(const int* __restrict__ src,
                                                 const int* __restrict__ dst,
                                                 int* __restrict__ bin_cnt,   // stride CNTSTRIDE
                                                 int* __restrict__ ovf_cnt,
                                                 unsigned int* __restrict__ ovf,
                                                 unsigned int* __restrict__ ebin,
                                                 int E, int nbin) {
    __shared__ int h[MAXBIN];
    __shared__ int base_s[MAXBIN];
    int t = threadIdx.x;
    for (int k = t; k < nbin; k += 256) h[k] = 0;
    __syncthreads();
    int per = E / gridDim.x;
    int ebeg = blockIdx.x * per;
    int eend = (blockIdx.x + 1 == gridDim.x) ? E : ebeg + per;
    for (int i = ebeg + t; i < eend; i += 256)
        atomicAdd(&h[dst[i] >> BINSHIFT], 1);
    __syncthreads();
    for (int k = t; k < nbin; k += 256) {
        int c = h[k];
        base_s[k] = (c > 0) ? atomicAdd(&bin_cnt[k * CNTSTRIDE], c) : 0;
        h[k] = 0;   // reuse as local fill counter
    }
    __syncthreads();
    for (int i = ebeg + t; i < eend; i += 256) {
        unsigned int s = (unsigned int)src[i];
        unsigned int d = (unsigned int)dst[i];
        int b = (int)(d >> BINSHIFT);
        int pos = base_s[b] + atomicAdd(&h[b], 1);
        unsigned int packed = s | (d << 16);
        if (pos < CAP) ebin[(size_t)b * CAP + pos] = packed;
        else ovf[atomicAdd(ovf_cnt, 1)] = packed;   // ovf sized E: can never drop
    }
}

// ---------------- build pass 2: per-bin fill — row_ptr, deg, dinv, csr_src (u16) ----------------
// Block 0 additionally computes Wc = W2@Wfc and bc = b2@Wfc + bfc.
__global__ __launch_bounds__(256) void k_fill(const unsigned int* __restrict__ ebin,
                                              const int* __restrict__ bin_cnt,
                                              const int* __restrict__ ovf_cnt,
                                              const unsigned int* __restrict__ ovf,
                                              int* __restrict__ row_ptr,
                                              unsigned short* __restrict__ degu,
                                              unsigned short* __restrict__ csr_src,
                                              float* __restrict__ dinv,
                                              const float* __restrict__ W2,
                                              const float* __restrict__ Wfc,
                                              const float* __restrict__ b2,
                                              const float* __restrict__ bfc,
                                              float* __restrict__ Wc,
                                              float* __restrict__ bc,
                                              int N, int nbin) {
    __shared__ int cnt[BINW];
    __shared__ int excl[BINW];
    __shared__ int start[BINW];
    int k = blockIdx.x;
    int node0 = k * BINW;
    int nn = min(BINW, N - node0);
    int t = threadIdx.x;
    if (t < BINW) cnt[t] = 0;
    __syncthreads();
    int cnt_k = min(bin_cnt[k * CNTSTRIDE], CAP);
    const unsigned int* seg = ebin + (size_t)k * CAP;
    for (int i = t; i < cnt_k; i += 256)
        atomicAdd(&cnt[(seg[i] >> 16) & (BINW - 1)], 1);
    int novf = *ovf_cnt;
    for (int i = t; i < novf; i += 256) {
        unsigned int e = ovf[i];
        if ((int)(e >> (16 + BINSHIFT)) == k)
            atomicAdd(&cnt[(e >> 16) & (BINW - 1)], 1);
    }
    __syncthreads();
    if (t < BINW) excl[t] = (t < nn) ? cnt[t] : 0;
    __syncthreads();
    for (int off = 1; off < BINW; off <<= 1) {
        int u = 0;
        if (t < BINW && t >= off) u = excl[t - off];
        __syncthreads();
        if (t < BINW) excl[t] += u;   // inclusive scan
        __syncthreads();
    }
    if (t < nn) {
        int deg = cnt[t];
        int e0 = k * CAP + excl[t] - deg;   // absolute slot in csr_src (bins have holes)
        start[t] = e0;
        row_ptr[node0 + t] = e0;
        degu[node0 + t] = (unsigned short)deg;
        dinv[node0 + t] = rsqrtf((float)deg + 1.0f);
        cnt[t] = 0;                         // reuse as fill counter
    }
    __syncthreads();
    for (int i = t; i < cnt_k; i += 256) {
        unsigned int e = seg[i];
        int dl = (e >> 16) & (BINW - 1);
        int slot = start[dl] + atomicAdd(&cnt[dl], 1);
        csr_src[slot] = (unsigned short)(e & 0xffffu);
    }
    for (int i = t; i < novf; i += 256) {
        unsigned int e = ovf[i];
        if ((int)(e >> (16 + BINSHIFT)) == k) {
            int dl = (e >> 16) & (BINW - 1);
            int slot = start[dl] + atomicAdd(&cnt[dl], 1);
            csr_src[slot] = (unsigned short)(e & 0xffffu);
        }
    }
    // ---- block 0: fold Wc = W2 @ Wfc (128x2), bc = b2 @ Wfc + bfc ----
    if (k == 0) {
        int kk = t >> 1, j = t & 1;
        float acc = 0.f;
#pragma unroll 8
        for (int m = 0; m < OUT_DIM; ++m) acc += W2[kk * OUT_DIM + m] * Wfc[m * 2 + j];
        Wc[kk * 2 + j] = acc;
        if (kk == 0) {
            float b = 0.f;
#pragma unroll 8
            for (int m = 0; m < OUT_DIM; ++m) b += b2[m] * Wfc[m * 2 + j];
            bc[j] = b + bfc[j];
        }
    }
}

// ---------------- GEMM1: xw1h = fp16(dinv[row] * (x @ W1)) ----------------
// Block tile 128x128, 256 threads, 8 rows x 8 cols. A from global (16-lane
// broadcast). W staged in TWO 32KB half-K phases -> 3 blocks/CU (was 2 at 64KB).
__global__ __launch_bounds__(256) void k_gemm1(const float* __restrict__ x,
                                               const float* __restrict__ W,
                                               const float* __restrict__ dinv,
                                               __half* __restrict__ xwh, int N) {
    __shared__ float Ws[64][128];   // [k][col], half-K
    int tid = threadIdx.x;
    float4* Ws4 = (float4*)&Ws[0][0];
    int tx = tid & 15, ty = tid >> 4;
    int row0 = blockIdx.x * 128;
    int rows[8];
    const float* xr[8];
#pragma unroll
    for (int j = 0; j < 8; ++j) {
        int row = row0 + ty + 16 * j;
        rows[j] = row;
        if (row > N - 1) row = N - 1;
        xr[j] = x + (size_t)row * IN_DIM;
    }
    float4 aclo[8], achi[8];
#pragma unroll
    for (int j = 0; j < 8; ++j) {
        aclo[j] = make_float4(0.f, 0.f, 0.f, 0.f);
        achi[j] = make_float4(0.f, 0.f, 0.f, 0.f);
    }
#pragma unroll
    for (int ph = 0; ph < 2; ++ph) {
        const float4* W4 = (const float4*)(W + (size_t)ph * 64 * HID_DIM);
#pragma unroll
        for (int i = 0; i < 8; ++i) Ws4[tid + 256 * i] = W4[tid + 256 * i];
        __syncthreads();
#pragma unroll 2
        for (int k4 = 0; k4 < 16; ++k4) {
            float4 av[8];
#pragma unroll
            for (int j = 0; j < 8; ++j) av[j] = *(const float4*)(xr[j] + ph * 64 + k4 * 4);
#pragma unroll
            for (int kk = 0; kk < 4; ++kk) {
                float4 blo = *(const float4*)&Ws[k4 * 4 + kk][4 * tx];
                float4 bhi = *(const float4*)&Ws[k4 * 4 + kk][64 + 4 * tx];
#pragma unroll
                for (int j = 0; j < 8; ++j) {
                    float a = (kk == 0) ? av[j].x : (kk == 1) ? av[j].y : (kk == 2) ? av[j].z : av[j].w;
                    aclo[j].x += a * blo.x; aclo[j].y += a * blo.y;
                    aclo[j].z += a * blo.z; aclo[j].w += a * blo.w;
                    achi[j].x += a * bhi.x; achi[j].y += a * bhi.y;
                    achi[j].z += a * bhi.z; achi[j].w += a * bhi.w;
                }
            }
        }
        __syncthreads();
    }
#pragma unroll
    for (int j = 0; j < 8; ++j) {
        if (rows[j] < N) {
            float dd = dinv[rows[j]];
            union { __half2 h[2]; uint2 u; } lo, hi;
            lo.h[0] = __floats2half2_rn(aclo[j].x * dd, aclo[j].y * dd);
            lo.h[1] = __floats2half2_rn(aclo[j].z * dd, aclo[j].w * dd);
            hi.h[0] = __floats2half2_rn(achi[j].x * dd, achi[j].y * dd);
            hi.h[1] = __floats2half2_rn(achi[j].z * dd, achi[j].w * dd);
            uint2* p = (uint2*)(xwh + (size_t)rows[j] * HID_DIM);
            p[tx] = lo.u;
            p[16 + tx] = hi.u;
        }
    }
}

// ---------------- Layer-1 aggregation + bias + ReLU + (h1 @ Wc) epilogue ----------------
// h1 = relu(dinv[d]*(sum_s xwh[s] + xwh[d]) + b1)   (xwh pre-scaled by dinv)
// z[d] = dinv[d] * (h1 @ Wc).  4x-unrolled gather: 16 outstanding uint4 per wave.
__global__ __launch_bounds__(256) void k_agg1z(const int* __restrict__ row_ptr,
                                               const unsigned short* __restrict__ degu,
                                               const unsigned short* __restrict__ csr_src,
                                               const float* __restrict__ dinv,
                                               const __half* __restrict__ xwh,
                                               const float* __restrict__ b1,
                                               const float* __restrict__ Wc,
                                               float* __restrict__ z, int N) {
    constexpr int F = HID_DIM;
    constexpr int L = F / 8;       // 16 lanes per row, 16B/lane
    constexpr int EPW = 64 / L;    // 4 edge slots per wave
    __shared__ float Wcs[HID_DIM * 2];
    int tid = threadIdx.x;
    if (tid < 64) ((float4*)Wcs)[tid] = ((const float4*)Wc)[tid];
    __syncthreads();
    int node = (blockIdx.x * 256 + tid) >> 6;
    if (node >= N) return;
    int lane = tid & 63;
    int sub = lane / L;
    int c   = lane % L;
    int beg = row_ptr[node];
    int end = beg + degu[node];
    // hoisted loads (overlap with gather)
    float dd = dinv[node];
    uint4 us = *(const uint4*)(xwh + (size_t)node * F + c * 8);
    float4 b1a = *(const float4*)(b1 + c * 8);
    float4 b1b = *(const float4*)(b1 + c * 8 + 4);
    float a0 = 0.f, a1 = 0.f, a2 = 0.f, a3 = 0.f;
    float a4 = 0.f, a5 = 0.f, a6 = 0.f, a7 = 0.f;
    auto acc = [&](uint4 u) {
        float2 v0 = __half22float2(*(__half2*)&u.x);
        float2 v1 = __half22float2(*(__half2*)&u.y);
        float2 v2 = __half22float2(*(__half2*)&u.z);
        float2 v3 = __half22float2(*(__half2*)&u.w);
        a0 += v0.x; a1 += v0.y; a2 += v1.x; a3 += v1.y;
        a4 += v2.x; a5 += v2.y; a6 += v3.x; a7 += v3.y;
    };
    int j = beg + sub;
    for (; j + 3 * EPW < end; j += 4 * EPW) {
        int s0 = csr_src[j];
        int s1 = csr_src[j + EPW];
        int s2 = csr_src[j + 2 * EPW];
        int s3 = csr_src[j + 3 * EPW];
        uint4 u0 = *(const uint4*)(xwh + (size_t)s0 * F + c * 8);
        uint4 u1 = *(const uint4*)(xwh + (size_t)s1 * F + c * 8);
        uint4 u2 = *(const uint4*)(xwh + (size_t)s2 * F + c * 8);
        uint4 u3 = *(const uint4*)(xwh + (size_t)s3 * F + c * 8);
        acc(u0); acc(u1); acc(u2); acc(u3);
    }
    for (; j < end; j += EPW) {
        int s = csr_src[j];
        acc(*(const uint4*)(xwh + (size_t)s * F + c * 8));
    }
#pragma unroll
    for (int off = L; off < 64; off <<= 1) {
        a0 += __shfl_xor(a0, off); a1 += __shfl_xor(a1, off);
        a2 += __shfl_xor(a2, off); a3 += __shfl_xor(a3, off);
        a4 += __shfl_xor(a4, off); a5 += __shfl_xor(a5, off);
        a6 += __shfl_xor(a6, off); a7 += __shfl_xor(a7, off);
    }
    // all lanes now hold the full column sums for their c
    float2 v0 = __half22float2(*(__half2*)&us.x);
    float2 v1 = __half22float2(*(__half2*)&us.y);
    float2 v2 = __half22float2(*(__half2*)&us.z);
    float2 v3 = __half22float2(*(__half2*)&us.w);
    float h[8];
    h[0] = fmaxf((a0 + v0.x) * dd + b1a.x, 0.f);
    h[1] = fmaxf((a1 + v0.y) * dd + b1a.y, 0.f);
    h[2] = fmaxf((a2 + v1.x) * dd + b1a.z, 0.f);
    h[3] = fmaxf((a3 + v1.y) * dd + b1a.w, 0.f);
    h[4] = fmaxf((a4 + v2.x) * dd + b1b.x, 0.f);
    h[5] = fmaxf((a5 + v2.y) * dd + b1b.y, 0.f);
    h[6] = fmaxf((a6 + v3.x) * dd + b1b.z, 0.f);
    h[7] = fmaxf((a7 + v3.y) * dd + b1b.w, 0.f);
    float o0 = 0.f, o1 = 0.f;
#pragma unroll
    for (int k = 0; k < 8; ++k) {
        o0 += h[k] * Wcs[(c * 8 + k) * 2 + 0];
        o1 += h[k] * Wcs[(c * 8 + k) * 2 + 1];
    }
#pragma unroll
    for (int off = 1; off < L; off <<= 1) {
        o0 += __shfl_xor(o0, off);
        o1 += __shfl_xor(o1, off);
    }
    if (lane == 0) {
        float2 r; r.x = o0 * dd; r.y = o1 * dd;
        *(float2*)(z + (size_t)node * 2) = r;
    }
}

// ---------------- Layer-2 aggregation on z (2 floats/node) + bias + leaky ----------------
__global__ __launch_bounds__(256) void k_agg2(const int* __restrict__ row_ptr,
                                              const unsigned short* __restrict__ degu,
                                              const unsigned short* __restrict__ csr_src,
                                              const float* __restrict__ dinv,
                                              const float* __restrict__ z,
                                              const float* __restrict__ bc,
                                              float* __restrict__ out, int N) {
    int tid = threadIdx.x;
    int gwave = (blockIdx.x * 256 + tid) >> 6;
    int lane = tid & 63;
    int grp = lane >> 3, li = lane & 7;
    int node = gwave * 8 + grp;
    if (node >= N) return;
    int beg = row_ptr[node];
    int end = beg + degu[node];
    float s0 = 0.f, s1 = 0.f;
    int j = beg + li;
    for (; j + 8 < end; j += 16) {
        int sa = csr_src[j];
        int sb = csr_src[j + 8];
        float2 za = *(const float2*)(z + (size_t)sa * 2);
        float2 zb = *(const float2*)(z + (size_t)sb * 2);
        s0 += za.x + zb.x; s1 += za.y + zb.y;
    }
    if (j < end) {
        int s = csr_src[j];
        float2 zv = *(const float2*)(z + (size_t)s * 2);
        s0 += zv.x; s1 += zv.y;
    }
#pragma unroll
    for (int off = 1; off < 8; off <<= 1) {
        s0 += __shfl_xor(s0, off);
        s1 += __shfl_xor(s1, off);
    }
    if (li == 0) {
        float2 zs = *(const float2*)(z + (size_t)node * 2);
        float dd = dinv[node];
        float o0 = (s0 + zs.x) * dd + bc[0];
        float o1 = (s1 + zs.y) * dd + bc[1];
        float2 r;
        r.x = o0 > 0.f ? o0 : 0.01f * o0;
        r.y = o1 > 0.f ? o1 : 0.01f * o1;
        *(float2*)(out + (size_t)node * 2) = r;
    }
}

extern "C" void kernel_launch(void* const* d_in, const int* in_sizes, int n_in,
                              void* d_out, int out_size, void* d_ws, size_t ws_size,
                              hipStream_t stream) {
    const float* x   = (const float*)d_in[0];
    const int*   ei  = (const int*)d_in[1];
    const float* W1  = (const float*)d_in[2];
    const float* b1  = (const float*)d_in[3];
    const float* W2  = (const float*)d_in[4];
    const float* b2  = (const float*)d_in[5];
    const float* Wfc = (const float*)d_in[6];
    const float* bfc = (const float*)d_in[7];

    const int N = in_sizes[0] / IN_DIM;   // 50000
    const int E = in_sizes[1] / 2;        // 800000
    const int* src = ei;
    const int* dst = ei + E;
    const int nbin = (N + BINW - 1) / BINW;  // 391

    // Workspace layout (256B-aligned regions):
    char* base = (char*)d_ws;
    size_t off = 0;
    auto take = [&](size_t bytes) { size_t o = off; off = (off + bytes + 255) & ~(size_t)255; return (void*)(base + o); };
    int*    row_ptr  = (int*)take((size_t)N * 4);
    unsigned short* degu = (unsigned short*)take((size_t)N * 2);
    unsigned short* csr_src = (unsigned short*)take((size_t)nbin * CAP * 2);
    int*    bin_cnt  = (int*)take((size_t)(nbin * CNTSTRIDE + CNTSTRIDE) * 4);  // + ovf_cnt line
    int*    ovf_cnt  = bin_cnt + nbin * CNTSTRIDE;
    unsigned int* ovf = (unsigned int*)take((size_t)E * 4);     // worst-case, never dropped
    unsigned int* ebin = (unsigned int*)take((size_t)nbin * CAP * 4);
    float*  dinv     = (float*)take((size_t)N * 4);
    __half* xw1h     = (__half*)take((size_t)N * HID_DIM * 2);
    float*  zbuf     = (float*)take((size_t)N * 2 * 4);
    float*  Wc       = (float*)take((size_t)HID_DIM * 2 * 4);
    float*  bc       = (float*)take(2 * 4);

    // zero the padded counters (one line each) + overflow counter
    hipMemsetAsync(bin_cnt, 0, (size_t)(nbin * CNTSTRIDE + CNTSTRIDE) * 4, stream);

    // 2-kernel CSR build (split launches; cooperative grid.sync costs ~50us/sync
    // on MI355X — R9 post-mortem). Fixed-capacity bins kill both scan kernels.
    k_scatter<<<256, 256, 0, stream>>>(src, dst, bin_cnt, ovf_cnt, ovf, ebin, E, nbin);
    k_fill<<<nbin, 256, 0, stream>>>(ebin, bin_cnt, ovf_cnt, ovf, row_ptr, degu,
                                     csr_src, dinv, W2, Wfc, b2, bfc, Wc, bc, N, nbin);

    const int nTile = (N + 127) / 128;

    // Layer 1 GEMM
    k_gemm1<<<nTile, 256, 0, stream>>>(x, W1, dinv, xw1h, N);
    // Layer-1 aggregation + relu + folded 128x2 GEMV -> z
    k_agg1z<<<(N + 3) / 4, 256, 0, stream>>>(row_ptr, degu, csr_src, dinv, xw1h, b1, Wc, zbuf, N);
    // Layer-2 aggregation on z + bias + leaky -> out
    const int nAgg2 = ((N + 7) / 8 * 64 + 255) / 256;
    k_agg2<<<nAgg2, 256, 0, stream>>>(row_ptr, degu, csr_src, dinv, zbuf, bc, (float*)d_out, N);
}